// Round 1
// baseline (235.948 us; speedup 1.0000x reference)
//
#include <hip/hip_runtime.h>
#include <hip/hip_fp16.h>

#define TT    64        // output tokens per block
#define HALO  9         // (KERNEL_SIZE-1)*DILATION
#define NTOK  73        // TT + HALO
#define XSTR  132       // s_xn row stride in halves (even, non-pow2)
#define EPS   1.1920929e-07f

typedef __attribute__((ext_vector_type(8))) _Float16 f16x8;
typedef __attribute__((ext_vector_type(4))) float f32x4;

// sum over each 16-lane row via DPP rotate-butterfly: pure VALU, no LDS pipe.
template<int CTRL>
__device__ __forceinline__ float dpp_add(float x) {
    int y = __builtin_amdgcn_update_dpp(0, __float_as_int(x), CTRL, 0xF, 0xF, true);
    return x + __int_as_float(y);
}
__device__ __forceinline__ float redsum16(float x) {
    x = dpp_add<0x128>(x);   // row_ror:8
    x = dpp_add<0x124>(x);   // row_ror:4
    x = dpp_add<0x122>(x);   // row_ror:2
    x = dpp_add<0x121>(x);   // row_ror:1
    return x;
}

__device__ __forceinline__ float fast_rcp(float x) {
    return __builtin_amdgcn_rcpf(x);
}

extern "C" __global__ __launch_bounds__(320, 6)
void engram_fused(const float* __restrict__ emb,   // [16,8192,32]
                  const float* __restrict__ hid,   // [16,8192,4,32]
                  const float* __restrict__ Wv,    // [32,32]
                  const float* __restrict__ bv,    // [32]
                  const float* __restrict__ Wk,    // [4,32,32]
                  const float* __restrict__ bk,    // [4,32]
                  const float* __restrict__ n1w,   // [4,32]
                  const float* __restrict__ n2w,   // [4,32]
                  const float* __restrict__ cnw,   // [4,32]
                  const float* __restrict__ cw,    // [128,1,4]
                  float* __restrict__ out)         // [16,8192,128]
{
    __shared__ __align__(16) __half s_xn[NTOK * XSTR];   // x_norm handoff (f16) — ONLY LDS now

    const int tid  = threadIdx.x;
    const int b    = blockIdx.x >> 7;
    const int tile = blockIdx.x & 127;
    const int t0   = tile * TT;

    const int wv  = tid >> 6;     // 0..4  (MFMA m-tile)
    const int ln  = tid & 63;
    const int l15 = ln & 15;
    const int q   = ln >> 4;
    const int ibase = wv * 16 + q * 4;   // token row = ibase + r

    // ======== phase 0: issue ALL long-latency loads up front (MLP) ========

    // hid stream (64 MB, the big one): 16 independent float2 loads, branchless.
    // Channel pair per lane = (2*l15, 2*l15+1) to match permuted MFMA columns.
    float2 q2[4][4];
    float  okm[4];
    #pragma unroll
    for (int r = 0; r < 4; ++r) {
        int t = t0 - HALO + ibase + r;
        okm[r] = (t >= 0 && t < 8192) ? 1.f : 0.f;
        int tc = t < 0 ? 0 : (t > 8191 ? 8191 : t);
        const float2* qp = (const float2*)&hid[(size_t)((b << 13) + tc) * 128];
        #pragma unroll
        for (int g = 0; g < 4; ++g) q2[r][g] = qp[g * 16 + l15];
    }

    // emb A-fragment: branchless clamp + mask
    float4 f0, f1;
    float amask;
    {
        const int tA = t0 - HALO + wv * 16 + l15;
        amask = (tA >= 0 && tA < 8192) ? 1.f : 0.f;
        const int tAc = tA < 0 ? 0 : (tA > 8191 ? 8191 : tA);
        const float4* p = (const float4*)&emb[(size_t)((b << 13) + tAc) * 32 + q * 8];
        f0 = p[0];
        f1 = p[1];
    }

    // biases + norm weights, float2 per lane (channels 2*l15, 2*l15+1)
    const float2 bv2 = ((const float2*)bv)[l15];
    float2 bk2[4], wn1[4], wn2[4], wcn[4];
    #pragma unroll
    for (int g = 0; g < 4; ++g) {
        bk2[g] = ((const float2*)(bk  + g * 32))[l15];
        wn1[g] = ((const float2*)(n1w + g * 32))[l15];
        wn2[g] = ((const float2*)(n2w + g * 32))[l15];
        wcn[g] = ((const float2*)(cnw + g * 32))[l15];
    }

    // ======== MFMA: 10 tiles, permuted columns ========
    f16x8 a;
    a[0] = (_Float16)(amask * f0.x); a[1] = (_Float16)(amask * f0.y);
    a[2] = (_Float16)(amask * f0.z); a[3] = (_Float16)(amask * f0.w);
    a[4] = (_Float16)(amask * f1.x); a[5] = (_Float16)(amask * f1.y);
    a[6] = (_Float16)(amask * f1.z); a[7] = (_Float16)(amask * f1.w);

    // Tile nt = 2p+e: column l15 <- weight row ch = 2*l15+e of (p==0 ? Wv : Wk[p-1]).
    // So lane's D pair (D[2p],D[2p+1]) = channels (2*l15, 2*l15+1). Natural order.
    f32x4 D[10];
    #pragma unroll
    for (int nt = 0; nt < 10; ++nt) {
        const int e = nt & 1, p = nt >> 1;
        const int ch = 2 * l15 + e;
        const float* wrow = (p == 0) ? &Wv[ch * 32] : &Wk[((p - 1) * 32 + ch) * 32];
        float4 w0 = ((const float4*)wrow)[q * 2];
        float4 w1 = ((const float4*)wrow)[q * 2 + 1];
        f16x8 bf;
        bf[0] = (_Float16)w0.x; bf[1] = (_Float16)w0.y;
        bf[2] = (_Float16)w0.z; bf[3] = (_Float16)w0.w;
        bf[4] = (_Float16)w1.x; bf[5] = (_Float16)w1.y;
        bf[6] = (_Float16)w1.z; bf[7] = (_Float16)w1.w;
        const float bias = (p == 0) ? (e ? bv2.y : bv2.x)
                                    : (e ? bk2[p - 1].y : bk2[p - 1].x);
        f32x4 c = {bias, bias, bias, bias};
        D[nt] = __builtin_amdgcn_mfma_f32_16x16x32_f16(a, bf, c, 0, 0, 0);
    }

    // ======== norms + gate + x_norm: 3 INDEPENDENT reductions per g ========
    // gates kept in registers for the owner-lane conv phase (statically indexed)
    float gs4[4][4];
    #pragma unroll
    for (int r = 0; r < 4; ++r) {
        const int i = ibase + r;
        const float V0 = D[0][r], V1 = D[1][r];
        float msv = redsum16(V0 * V0 + V1 * V1);   // Σ value² over 32 ch
        float xn[4][2];
        #pragma unroll
        for (int g = 0; g < 4; ++g) {
            const float K0 = D[2 + 2 * g][r], K1 = D[3 + 2 * g][r];
            const float q0 = q2[r][g].x * okm[r], q1 = q2[r][g].y * okm[r];
            // three independent DPP chains (interleave in the pipe)
            float msk = redsum16(K0 * K0 + K1 * K1);
            float msq = redsum16(q0 * q0 + q1 * q1);
            float dr  = redsum16(K0 * wn1[g].x * q0 * wn2[g].x
                               + K1 * wn1[g].y * q1 * wn2[g].y);
            float rk = rsqrtf(msk * (1.f / 32.f) + EPS);
            float rq = rsqrtf(msq * (1.f / 32.f) + EPS);
            float dot = dr * rk * rq * 0.17677669529663689f;   // /sqrt(32)
            float sa = sqrtf(fmaxf(fabsf(dot), 1e-6f));
            float gate = fast_rcp(1.f + __expf(-copysignf(sa, dot)));
            gs4[r][g] = gate;
            float sc = gate * rsqrtf(gate * gate * msv * (1.f / 32.f) + EPS);
            xn[g][0] = sc * V0 * wcn[g].x;
            xn[g][1] = sc * V1 * wcn[g].y;
        }
        if (i < NTOK) {
            // causal zero-pad: conv input is literally zero for t<0 (okm[r]==0 there)
            #pragma unroll
            for (int g = 0; g < 4; ++g) {
                __half2 h2 = __floats2half2_rn(okm[r] * xn[g][0], okm[r] * xn[g][1]);
                *(__half2*)&s_xn[i * XSTR + g * 32 + 2 * l15] = h2;
            }
        }
    }
    __syncthreads();

    // ======== phase 2: owner-lane dilated depthwise conv + SiLU + residual ====
    // Lane that produced token i = ibase+r owns output token j = i-HALO for its
    // channel pair (2*l15, 2*l15+1) in every group g. Value pair and gates are
    // already in registers (D[0][r], D[1][r], gs4[r][g]); only x_norm comes
    // from LDS (rows j, j+3, j+6, j+9).
    const float4* cw4p = (const float4*)cw;
    #pragma unroll
    for (int g = 0; g < 4; ++g) {
        const int ch = g * 32 + 2 * l15;
        const float4 wA = cw4p[ch];        // taps for channel ch
        const float4 wB = cw4p[ch + 1];    // taps for channel ch+1
        #pragma unroll
        for (int r = 0; r < 4; ++r) {
            const int i = ibase + r;
            const int j = i - HALO;
            if (i >= HALO && i < NTOK) {
                float y0 = 0.f, y1 = 0.f;
                #pragma unroll
                for (int k = 0; k < 4; ++k) {
                    float2 x = __half22float2(
                        *(const __half2*)&s_xn[(j + 3 * k) * XSTR + ch]);
                    const float wk0 = (k == 0) ? wA.x : (k == 1) ? wA.y
                                    : (k == 2) ? wA.z : wA.w;
                    const float wk1 = (k == 0) ? wB.x : (k == 1) ? wB.y
                                    : (k == 2) ? wB.z : wB.w;
                    y0 = fmaf(x.x, wk0, y0);
                    y1 = fmaf(x.y, wk1, y1);
                }
                const float gg = gs4[r][g];
                float2 o;
                o.x = gg * D[0][r] + y0 * fast_rcp(1.f + __expf(-y0));
                o.y = gg * D[1][r] + y1 * fast_rcp(1.f + __expf(-y1));
                *(float2*)&out[(size_t)((b << 13) + t0 + j) * 128 + ch] = o;
            }
        }
    }
}

extern "C" void kernel_launch(void* const* d_in, const int* in_sizes, int n_in,
                              void* d_out, int out_size, void* d_ws, size_t ws_size,
                              hipStream_t stream) {
    const float* emb = (const float*)d_in[0];
    const float* hid = (const float*)d_in[1];
    const float* Wv  = (const float*)d_in[2];
    const float* bvp = (const float*)d_in[3];
    const float* Wk  = (const float*)d_in[4];
    const float* bkp = (const float*)d_in[5];
    const float* n1  = (const float*)d_in[6];
    const float* n2  = (const float*)d_in[7];
    const float* cn  = (const float*)d_in[8];
    const float* cwp = (const float*)d_in[9];
    float* out = (float*)d_out;

    dim3 grid(16 * 128);   // b * (8192/64)
    dim3 block(320);       // 5 waves = 5 MFMA m-tiles
    engram_fused<<<grid, block, 0, stream>>>(emb, hid, Wv, bvp, Wk, bkp, n1, n2, cn, cwp, out);
}

// Round 2
// 218.606 us; speedup vs baseline: 1.0793x; 1.0793x over previous
//
#include <hip/hip_runtime.h>
#include <hip/hip_fp16.h>

#define TT    64        // output tokens per block
#define HALO  9         // (KERNEL_SIZE-1)*DILATION
#define NTOK  73        // TT + HALO
#define XSTR  132       // s_xn row stride in halves (even, non-pow2)
#define EPS   1.1920929e-07f

typedef __attribute__((ext_vector_type(8))) _Float16 f16x8;
typedef __attribute__((ext_vector_type(4))) float f32x4;

// sum over each 16-lane row via DPP rotate-butterfly: pure VALU, no LDS pipe.
template<int CTRL>
__device__ __forceinline__ float dpp_add(float x) {
    int y = __builtin_amdgcn_update_dpp(0, __float_as_int(x), CTRL, 0xF, 0xF, true);
    return x + __int_as_float(y);
}
__device__ __forceinline__ float redsum16(float x) {
    x = dpp_add<0x128>(x);   // row_ror:8
    x = dpp_add<0x124>(x);   // row_ror:4
    x = dpp_add<0x122>(x);   // row_ror:2
    x = dpp_add<0x121>(x);   // row_ror:1
    return x;
}

__device__ __forceinline__ float fast_rcp(float x) {
    return __builtin_amdgcn_rcpf(x);
}

// (320,3): cap ~170 VGPR — round 1 proved (320,6) forces an ~8KB/wave scratch
// spill of the phase-1 working set (D[10]+q2+weights), doubling HBM writes.
extern "C" __global__ __launch_bounds__(320, 3)
void engram_fused(const float* __restrict__ emb,   // [16,8192,32]
                  const float* __restrict__ hid,   // [16,8192,4,32]
                  const float* __restrict__ Wv,    // [32,32]
                  const float* __restrict__ bv,    // [32]
                  const float* __restrict__ Wk,    // [4,32,32]
                  const float* __restrict__ bk,    // [4,32]
                  const float* __restrict__ n1w,   // [4,32]
                  const float* __restrict__ n2w,   // [4,32]
                  const float* __restrict__ cnw,   // [4,32]
                  const float* __restrict__ cw,    // [128,1,4]
                  float* __restrict__ out)         // [16,8192,128]
{
    __shared__ __align__(16) __half s_xn[NTOK * XSTR];   // x_norm handoff (f16) — ONLY LDS

    const int tid  = threadIdx.x;
    const int b    = blockIdx.x >> 7;
    const int tile = blockIdx.x & 127;
    const int t0   = tile * TT;

    const int wv  = tid >> 6;     // 0..4  (MFMA m-tile)
    const int ln  = tid & 63;
    const int l15 = ln & 15;
    const int q   = ln >> 4;
    const int ibase = wv * 16 + q * 4;   // token row = ibase + r

    // ======== phase 0: issue ALL long-latency loads up front (MLP) ========

    // hid stream (64 MB, the big one): 16 independent float2 loads, branchless.
    // Channel pair per lane = (2*l15, 2*l15+1) to match permuted MFMA columns.
    float2 q2[4][4];
    float  okm[4];
    #pragma unroll
    for (int r = 0; r < 4; ++r) {
        int t = t0 - HALO + ibase + r;
        okm[r] = (t >= 0 && t < 8192) ? 1.f : 0.f;
        int tc = t < 0 ? 0 : (t > 8191 ? 8191 : t);
        const float2* qp = (const float2*)&hid[(size_t)((b << 13) + tc) * 128];
        #pragma unroll
        for (int g = 0; g < 4; ++g) q2[r][g] = qp[g * 16 + l15];
    }

    // emb A-fragment: branchless clamp + mask
    float4 f0, f1;
    float amask;
    {
        const int tA = t0 - HALO + wv * 16 + l15;
        amask = (tA >= 0 && tA < 8192) ? 1.f : 0.f;
        const int tAc = tA < 0 ? 0 : (tA > 8191 ? 8191 : tA);
        const float4* p = (const float4*)&emb[(size_t)((b << 13) + tAc) * 32 + q * 8];
        f0 = p[0];
        f1 = p[1];
    }

    // biases + norm weights, float2 per lane (channels 2*l15, 2*l15+1)
    const float2 bv2 = ((const float2*)bv)[l15];
    float2 bk2[4], wn1[4], wn2[4], wcn[4];
    #pragma unroll
    for (int g = 0; g < 4; ++g) {
        bk2[g] = ((const float2*)(bk  + g * 32))[l15];
        wn1[g] = ((const float2*)(n1w + g * 32))[l15];
        wn2[g] = ((const float2*)(n2w + g * 32))[l15];
        wcn[g] = ((const float2*)(cnw + g * 32))[l15];
    }

    // ======== MFMA: 10 tiles, permuted columns ========
    f16x8 a;
    a[0] = (_Float16)(amask * f0.x); a[1] = (_Float16)(amask * f0.y);
    a[2] = (_Float16)(amask * f0.z); a[3] = (_Float16)(amask * f0.w);
    a[4] = (_Float16)(amask * f1.x); a[5] = (_Float16)(amask * f1.y);
    a[6] = (_Float16)(amask * f1.z); a[7] = (_Float16)(amask * f1.w);

    // Tile nt = 2p+e: column l15 <- weight row ch = 2*l15+e of (p==0 ? Wv : Wk[p-1]).
    // So lane's D pair (D[2p],D[2p+1]) = channels (2*l15, 2*l15+1). Natural order.
    f32x4 D[10];
    #pragma unroll
    for (int nt = 0; nt < 10; ++nt) {
        const int e = nt & 1, p = nt >> 1;
        const int ch = 2 * l15 + e;
        const float* wrow = (p == 0) ? &Wv[ch * 32] : &Wk[((p - 1) * 32 + ch) * 32];
        float4 w0 = ((const float4*)wrow)[q * 2];
        float4 w1 = ((const float4*)wrow)[q * 2 + 1];
        f16x8 bf;
        bf[0] = (_Float16)w0.x; bf[1] = (_Float16)w0.y;
        bf[2] = (_Float16)w0.z; bf[3] = (_Float16)w0.w;
        bf[4] = (_Float16)w1.x; bf[5] = (_Float16)w1.y;
        bf[6] = (_Float16)w1.z; bf[7] = (_Float16)w1.w;
        const float bias = (p == 0) ? (e ? bv2.y : bv2.x)
                                    : (e ? bk2[p - 1].y : bk2[p - 1].x);
        f32x4 c = {bias, bias, bias, bias};
        D[nt] = __builtin_amdgcn_mfma_f32_16x16x32_f16(a, bf, c, 0, 0, 0);
    }

    // ======== norms + gate + x_norm: 3 INDEPENDENT reductions per g ========
    // gates kept in registers for the owner-lane conv phase (statically indexed)
    float gs4[4][4];
    #pragma unroll
    for (int r = 0; r < 4; ++r) {
        const int i = ibase + r;
        const float V0 = D[0][r], V1 = D[1][r];
        float msv = redsum16(V0 * V0 + V1 * V1);   // Σ value² over 32 ch
        float xn[4][2];
        #pragma unroll
        for (int g = 0; g < 4; ++g) {
            const float K0 = D[2 + 2 * g][r], K1 = D[3 + 2 * g][r];
            const float q0 = q2[r][g].x * okm[r], q1 = q2[r][g].y * okm[r];
            // three independent DPP chains (interleave in the pipe)
            float msk = redsum16(K0 * K0 + K1 * K1);
            float msq = redsum16(q0 * q0 + q1 * q1);
            float dr  = redsum16(K0 * wn1[g].x * q0 * wn2[g].x
                               + K1 * wn1[g].y * q1 * wn2[g].y);
            float rk = rsqrtf(msk * (1.f / 32.f) + EPS);
            float rq = rsqrtf(msq * (1.f / 32.f) + EPS);
            float dot = dr * rk * rq * 0.17677669529663689f;   // /sqrt(32)
            float sa = sqrtf(fmaxf(fabsf(dot), 1e-6f));
            float gate = fast_rcp(1.f + __expf(-copysignf(sa, dot)));
            gs4[r][g] = gate;
            float sc = gate * rsqrtf(gate * gate * msv * (1.f / 32.f) + EPS);
            xn[g][0] = sc * V0 * wcn[g].x;
            xn[g][1] = sc * V1 * wcn[g].y;
        }
        if (i < NTOK) {
            // causal zero-pad: conv input is literally zero for t<0 (okm[r]==0 there)
            #pragma unroll
            for (int g = 0; g < 4; ++g) {
                __half2 h2 = __floats2half2_rn(okm[r] * xn[g][0], okm[r] * xn[g][1]);
                *(__half2*)&s_xn[i * XSTR + g * 32 + 2 * l15] = h2;
            }
        }
    }
    __syncthreads();

    // ======== phase 2: owner-lane dilated depthwise conv + SiLU + residual ====
    // Lane that produced token i = ibase+r owns output token j = i-HALO for its
    // channel pair (2*l15, 2*l15+1) in every group g. Value pair and gates are
    // already in registers (D[0][r], D[1][r], gs4[r][g]); only x_norm comes
    // from LDS (rows j, j+3, j+6, j+9).
    const float4* cw4p = (const float4*)cw;
    #pragma unroll
    for (int g = 0; g < 4; ++g) {
        const int ch = g * 32 + 2 * l15;
        const float4 wA = cw4p[ch];        // taps for channel ch
        const float4 wB = cw4p[ch + 1];    // taps for channel ch+1
        #pragma unroll
        for (int r = 0; r < 4; ++r) {
            const int i = ibase + r;
            const int j = i - HALO;
            if (i >= HALO && i < NTOK) {
                float y0 = 0.f, y1 = 0.f;
                #pragma unroll
                for (int k = 0; k < 4; ++k) {
                    float2 x = __half22float2(
                        *(const __half2*)&s_xn[(j + 3 * k) * XSTR + ch]);
                    const float wk0 = (k == 0) ? wA.x : (k == 1) ? wA.y
                                    : (k == 2) ? wA.z : wA.w;
                    const float wk1 = (k == 0) ? wB.x : (k == 1) ? wB.y
                                    : (k == 2) ? wB.z : wB.w;
                    y0 = fmaf(x.x, wk0, y0);
                    y1 = fmaf(x.y, wk1, y1);
                }
                const float gg = gs4[r][g];
                float2 o;
                o.x = gg * D[0][r] + y0 * fast_rcp(1.f + __expf(-y0));
                o.y = gg * D[1][r] + y1 * fast_rcp(1.f + __expf(-y1));
                *(float2*)&out[(size_t)((b << 13) + t0 + j) * 128 + ch] = o;
            }
        }
    }
}

extern "C" void kernel_launch(void* const* d_in, const int* in_sizes, int n_in,
                              void* d_out, int out_size, void* d_ws, size_t ws_size,
                              hipStream_t stream) {
    const float* emb = (const float*)d_in[0];
    const float* hid = (const float*)d_in[1];
    const float* Wv  = (const float*)d_in[2];
    const float* bvp = (const float*)d_in[3];
    const float* Wk  = (const float*)d_in[4];
    const float* bkp = (const float*)d_in[5];
    const float* n1  = (const float*)d_in[6];
    const float* n2  = (const float*)d_in[7];
    const float* cn  = (const float*)d_in[8];
    const float* cwp = (const float*)d_in[9];
    float* out = (float*)d_out;

    dim3 grid(16 * 128);   // b * (8192/64)
    dim3 block(320);       // 5 waves = 5 MFMA m-tiles
    engram_fused<<<grid, block, 0, stream>>>(emb, hid, Wv, bvp, Wk, bkp, n1, n2, cn, cwp, out);
}